// Round 1
// baseline (6988.729 us; speedup 1.0000x reference)
//
#include <hip/hip_runtime.h>
#include <hip/hip_bf16.h>
#include <math.h>

// ---- problem constants ----
#define BATCH   2
#define SEQ     2048
#define D_IN    2048
#define D_OUT   2048
#define NHEAD   16
#define QK_ROPE 64
#define QK_NOPE 64
#define QK_HEAD 128          // QK_NOPE + QK_ROPE
#define V_HEAD  128
#define KV_RANK 512
#define D_KVA   576          // KV_RANK + QK_ROPE
#define D_KVB   3072         // NHEAD * (QK_NOPE + V_HEAD) = 16*192
#define NTOK    (BATCH*SEQ)  // 4096
#define THETA_F 10000.0f
#define EPS_F   1e-6f

// ------------------------------------------------------------------
// Tiled fp32 GEMM: C[M,N] = A[M,K] @ B[K,N], all row-major.
// 64x64 tile, 16x16 threads, 4x4 per thread, K-step 16.
// Requires M%64==0, N%64==0, K%16==0 (true for all calls here).
// ------------------------------------------------------------------
__global__ __launch_bounds__(256) void gemm_f32(const float* __restrict__ A,
                                                const float* __restrict__ B,
                                                float* __restrict__ C,
                                                int M, int N, int K) {
    __shared__ float As[16][65];
    __shared__ float Bs[16][65];
    const int tx = threadIdx.x, ty = threadIdx.y;
    const int tid = ty * 16 + tx;
    const int row0 = blockIdx.y * 64;
    const int col0 = blockIdx.x * 64;

    float acc[4][4];
#pragma unroll
    for (int i = 0; i < 4; ++i)
#pragma unroll
        for (int j = 0; j < 4; ++j) acc[i][j] = 0.f;

    for (int k0 = 0; k0 < K; k0 += 16) {
        // load A tile: 64 rows x 16 k
#pragma unroll
        for (int i = 0; i < 4; ++i) {
            int idx = i * 256 + tid;
            int m = idx >> 4, k = idx & 15;
            As[k][m] = A[(size_t)(row0 + m) * K + k0 + k];
        }
        // load B tile: 16 k x 64 cols
#pragma unroll
        for (int i = 0; i < 4; ++i) {
            int idx = i * 256 + tid;
            int k = idx >> 6, n = idx & 63;
            Bs[k][n] = B[(size_t)(k0 + k) * N + col0 + n];
        }
        __syncthreads();
#pragma unroll
        for (int kk = 0; kk < 16; ++kk) {
            float a[4], b[4];
#pragma unroll
            for (int i = 0; i < 4; ++i) a[i] = As[kk][ty + 16 * i];
#pragma unroll
            for (int j = 0; j < 4; ++j) b[j] = Bs[kk][tx + 16 * j];
#pragma unroll
            for (int i = 0; i < 4; ++i)
#pragma unroll
                for (int j = 0; j < 4; ++j) acc[i][j] += a[i] * b[j];
        }
        __syncthreads();
    }
#pragma unroll
    for (int i = 0; i < 4; ++i)
#pragma unroll
        for (int j = 0; j < 4; ++j)
            C[(size_t)(row0 + ty + 16 * i) * N + col0 + tx + 16 * j] = acc[i][j];
}

// ------------------------------------------------------------------
// RMS norm over KV_RANK cols of kv -> c_norm. One block per row.
// ------------------------------------------------------------------
__global__ __launch_bounds__(256) void rmsnorm_kernel(const float* __restrict__ kv,
                                                      const float* __restrict__ w,
                                                      float* __restrict__ c_norm) {
    __shared__ float red[256];
    const int row = blockIdx.x;
    const int t = threadIdx.x;
    const float* src = kv + (size_t)row * D_KVA;
    float ss = 0.f;
    for (int c = t; c < KV_RANK; c += 256) {
        float v = src[c];
        ss += v * v;
    }
    red[t] = ss;
    __syncthreads();
    for (int s = 128; s > 0; s >>= 1) {
        if (t < s) red[t] += red[t + s];
        __syncthreads();
    }
    const float inv = rsqrtf(red[0] / (float)KV_RANK + EPS_F);
    float* dst = c_norm + (size_t)row * KV_RANK;
    for (int c = t; c < KV_RANK; c += 256) dst[c] = src[c] * inv * w[c];
}

// ------------------------------------------------------------------
// RoPE on q_pe (in place inside q_all). One thread per (row,h,pair).
// ------------------------------------------------------------------
__global__ __launch_bounds__(256) void rope_q_kernel(float* __restrict__ q_all) {
    const int gid = blockIdx.x * 256 + threadIdx.x;  // < NTOK*NHEAD*32
    const int i = gid & 31;
    const int h = (gid >> 5) & (NHEAD - 1);
    const int row = gid >> 9;
    const int s = row & (SEQ - 1);
    const float freq = powf(THETA_F, -(float)(2 * i) / 64.0f);
    const float ang = (float)s * freq;
    const float c = cosf(ang), sn = sinf(ang);
    float* p = q_all + (size_t)row * (NHEAD * QK_HEAD) + h * QK_HEAD + QK_NOPE + 2 * i;
    const float x1 = p[0], x2 = p[1];
    p[0] = x1 * c - x2 * sn;
    p[1] = x2 * c + x1 * sn;
}

// ------------------------------------------------------------------
// RoPE on k_pe (from kv cols [512..575]) -> kpe[NTOK,64]. Head-indep.
// ------------------------------------------------------------------
__global__ __launch_bounds__(256) void rope_k_kernel(const float* __restrict__ kv,
                                                     float* __restrict__ kpe) {
    const int gid = blockIdx.x * 256 + threadIdx.x;  // < NTOK*32
    const int i = gid & 31;
    const int row = gid >> 5;
    const int s = row & (SEQ - 1);
    const float freq = powf(THETA_F, -(float)(2 * i) / 64.0f);
    const float ang = (float)s * freq;
    const float c = cosf(ang), sn = sinf(ang);
    const float* src = kv + (size_t)row * D_KVA + KV_RANK + 2 * i;
    const float x1 = src[0], x2 = src[1];
    kpe[(size_t)row * QK_ROPE + 2 * i]     = x1 * c - x2 * sn;
    kpe[(size_t)row * QK_ROPE + 2 * i + 1] = x2 * c + x1 * sn;
}

// ------------------------------------------------------------------
// Causal attention, one block (128 threads) per (q,h,b).
// Scores row kept in LDS (S=2048 -> 8KB). Two-pass softmax, then PV.
// ------------------------------------------------------------------
__global__ __launch_bounds__(128) void attn_kernel(const float* __restrict__ q_all,
                                                   const float* __restrict__ kv_dec,
                                                   const float* __restrict__ kpe,
                                                   float* __restrict__ attn_out) {
    __shared__ float sc[SEQ];
    __shared__ float qv[QK_HEAD];
    __shared__ float red[128];
    const int q = blockIdx.x;
    const int h = blockIdx.y;
    const int b = blockIdx.z;
    const int t = threadIdx.x;
    const int row = b * SEQ + q;
    const float scale = 0.08838834764831845f;  // 128^-0.5

    qv[t] = q_all[(size_t)row * (NHEAD * QK_HEAD) + h * QK_HEAD + t];
    __syncthreads();

    float lmax = -1e30f;
    for (int k = t; k <= q; k += 128) {
        const float* kn = kv_dec + (size_t)(b * SEQ + k) * D_KVB + h * 192;
        const float* kp = kpe + (size_t)(b * SEQ + k) * QK_ROPE;
        float d = 0.f;
#pragma unroll
        for (int j = 0; j < QK_NOPE; ++j) d += qv[j] * kn[j];
#pragma unroll
        for (int j = 0; j < QK_ROPE; ++j) d += qv[QK_NOPE + j] * kp[j];
        d *= scale;
        sc[k] = d;
        lmax = fmaxf(lmax, d);
    }
    red[t] = lmax;
    __syncthreads();
    for (int s = 64; s > 0; s >>= 1) {
        if (t < s) red[t] = fmaxf(red[t], red[t + s]);
        __syncthreads();
    }
    const float m = red[0];
    __syncthreads();

    float lsum = 0.f;
    for (int k = t; k <= q; k += 128) {
        float p = __expf(sc[k] - m);
        sc[k] = p;
        lsum += p;
    }
    red[t] = lsum;
    __syncthreads();
    for (int s = 64; s > 0; s >>= 1) {
        if (t < s) red[t] += red[t + s];
        __syncthreads();
    }
    const float inv = 1.0f / red[0];

    // PV: thread t owns output dim t (V_HEAD == 128 == blockDim)
    float o = 0.f;
    const float* vbase = kv_dec + (size_t)b * SEQ * D_KVB + h * 192 + QK_NOPE;
    for (int k = 0; k <= q; ++k) o += sc[k] * vbase[(size_t)k * D_KVB + t];
    attn_out[(size_t)row * (NHEAD * V_HEAD) + h * V_HEAD + t] = o * inv;
}

// ------------------------------------------------------------------
extern "C" void kernel_launch(void* const* d_in, const int* in_sizes, int n_in,
                              void* d_out, int out_size, void* d_ws, size_t ws_size,
                              hipStream_t stream) {
    const float* x         = (const float*)d_in[0];
    const float* w_query   = (const float*)d_in[1];
    const float* wkv_a     = (const float*)d_in[2];
    const float* wkv_b     = (const float*)d_in[3];
    const float* kv_norm_w = (const float*)d_in[4];
    const float* out_proj  = (const float*)d_in[5];
    float* out = (float*)d_out;

    // workspace layout (floats)
    float* ws = (float*)d_ws;
    float* q_all    = ws;                               // NTOK * 2048
    float* kv       = q_all + (size_t)NTOK * 2048;      // NTOK * 576
    float* c_norm   = kv + (size_t)NTOK * D_KVA;        // NTOK * 512
    float* kpe      = c_norm + (size_t)NTOK * KV_RANK;  // NTOK * 64
    float* kv_dec   = kpe + (size_t)NTOK * QK_ROPE;     // NTOK * 3072
    float* attn_out = kv_dec + (size_t)NTOK * D_KVB;    // NTOK * 2048

    dim3 blk(16, 16);

    // q = x @ w_query : [4096,2048] @ [2048,2048]
    gemm_f32<<<dim3(2048 / 64, NTOK / 64), blk, 0, stream>>>(x, w_query, q_all, NTOK, 2048, D_IN);
    // kv = x @ wkv_a : [4096,2048] @ [2048,576]
    gemm_f32<<<dim3(D_KVA / 64, NTOK / 64), blk, 0, stream>>>(x, wkv_a, kv, NTOK, D_KVA, D_IN);
    // c_norm = rms_norm(kv[:, :512]) * w
    rmsnorm_kernel<<<NTOK, 256, 0, stream>>>(kv, kv_norm_w, c_norm);
    // kv_dec = c_norm @ wkv_b : [4096,512] @ [512,3072]
    gemm_f32<<<dim3(D_KVB / 64, NTOK / 64), blk, 0, stream>>>(c_norm, wkv_b, kv_dec, NTOK, D_KVB, KV_RANK);
    // rope q_pe in place
    rope_q_kernel<<<(NTOK * NHEAD * 32) / 256, 256, 0, stream>>>(q_all);
    // rope k_pe -> kpe
    rope_k_kernel<<<(NTOK * 32) / 256, 256, 0, stream>>>(kv, kpe);
    // attention
    attn_kernel<<<dim3(SEQ, NHEAD, BATCH), 128, 0, stream>>>(q_all, kv_dec, kpe, attn_out);
    // out = attn_out @ out_proj : [4096,2048] @ [2048,2048]
    gemm_f32<<<dim3(D_OUT / 64, NTOK / 64), blk, 0, stream>>>(attn_out, out_proj, out, NTOK, D_OUT, D_IN);
}

// Round 2
// 2485.352 us; speedup vs baseline: 2.8120x; 2.8120x over previous
//
#include <hip/hip_runtime.h>
#include <hip/hip_bf16.h>
#include <math.h>

// ---- problem constants ----
#define BATCH   2
#define SEQ     2048
#define D_IN    2048
#define D_OUT   2048
#define NHEAD   16
#define QK_ROPE 64
#define QK_NOPE 64
#define QK_HEAD 128          // QK_NOPE + QK_ROPE
#define V_HEAD  128
#define KV_RANK 512
#define D_KVA   576          // KV_RANK + QK_ROPE
#define D_KVB   3072         // NHEAD * (QK_NOPE + V_HEAD) = 16*192
#define NTOK    (BATCH*SEQ)  // 4096
#define THETA_F 10000.0f
#define EPS_F   1e-6f

typedef short bf16x8 __attribute__((ext_vector_type(8)));
typedef float f32x4  __attribute__((ext_vector_type(4)));

__device__ __forceinline__ unsigned short f2bf(float f) {
    unsigned u = __float_as_uint(f);
    unsigned r = (u + 0x7fffu + ((u >> 16) & 1u)) >> 16;
    return (unsigned short)r;
}

// ------------------------------------------------------------------
// Tiled fp32 GEMM: C[M,N] = A[M,K] @ B[K,N], all row-major.
// 64x64 tile, 16x16 threads, 4x4 per thread, K-step 16.
// ------------------------------------------------------------------
__global__ __launch_bounds__(256) void gemm_f32(const float* __restrict__ A,
                                                const float* __restrict__ B,
                                                float* __restrict__ C,
                                                int M, int N, int K) {
    __shared__ float As[16][65];
    __shared__ float Bs[16][65];
    const int tx = threadIdx.x, ty = threadIdx.y;
    const int tid = ty * 16 + tx;
    const int row0 = blockIdx.y * 64;
    const int col0 = blockIdx.x * 64;

    float acc[4][4];
#pragma unroll
    for (int i = 0; i < 4; ++i)
#pragma unroll
        for (int j = 0; j < 4; ++j) acc[i][j] = 0.f;

    for (int k0 = 0; k0 < K; k0 += 16) {
#pragma unroll
        for (int i = 0; i < 4; ++i) {
            int idx = i * 256 + tid;
            int m = idx >> 4, k = idx & 15;
            As[k][m] = A[(size_t)(row0 + m) * K + k0 + k];
        }
#pragma unroll
        for (int i = 0; i < 4; ++i) {
            int idx = i * 256 + tid;
            int k = idx >> 6, n = idx & 63;
            Bs[k][n] = B[(size_t)(k0 + k) * N + col0 + n];
        }
        __syncthreads();
#pragma unroll
        for (int kk = 0; kk < 16; ++kk) {
            float a[4], b[4];
#pragma unroll
            for (int i = 0; i < 4; ++i) a[i] = As[kk][ty + 16 * i];
#pragma unroll
            for (int j = 0; j < 4; ++j) b[j] = Bs[kk][tx + 16 * j];
#pragma unroll
            for (int i = 0; i < 4; ++i)
#pragma unroll
                for (int j = 0; j < 4; ++j) acc[i][j] += a[i] * b[j];
        }
        __syncthreads();
    }
#pragma unroll
    for (int i = 0; i < 4; ++i)
#pragma unroll
        for (int j = 0; j < 4; ++j)
            C[(size_t)(row0 + ty + 16 * i) * N + col0 + tx + 16 * j] = acc[i][j];
}

// ------------------------------------------------------------------
__global__ __launch_bounds__(256) void rmsnorm_kernel(const float* __restrict__ kv,
                                                      const float* __restrict__ w,
                                                      float* __restrict__ c_norm) {
    __shared__ float red[256];
    const int row = blockIdx.x;
    const int t = threadIdx.x;
    const float* src = kv + (size_t)row * D_KVA;
    float ss = 0.f;
    for (int c = t; c < KV_RANK; c += 256) {
        float v = src[c];
        ss += v * v;
    }
    red[t] = ss;
    __syncthreads();
    for (int s = 128; s > 0; s >>= 1) {
        if (t < s) red[t] += red[t + s];
        __syncthreads();
    }
    const float inv = rsqrtf(red[0] / (float)KV_RANK + EPS_F);
    float* dst = c_norm + (size_t)row * KV_RANK;
    for (int c = t; c < KV_RANK; c += 256) dst[c] = src[c] * inv * w[c];
}

// ------------------------------------------------------------------
__global__ __launch_bounds__(256) void rope_q_kernel(float* __restrict__ q_all) {
    const int gid = blockIdx.x * 256 + threadIdx.x;  // < NTOK*NHEAD*32
    const int i = gid & 31;
    const int h = (gid >> 5) & (NHEAD - 1);
    const int row = gid >> 9;
    const int s = row & (SEQ - 1);
    const float freq = powf(THETA_F, -(float)(2 * i) / 64.0f);
    const float ang = (float)s * freq;
    const float c = cosf(ang), sn = sinf(ang);
    float* p = q_all + (size_t)row * (NHEAD * QK_HEAD) + h * QK_HEAD + QK_NOPE + 2 * i;
    const float x1 = p[0], x2 = p[1];
    p[0] = x1 * c - x2 * sn;
    p[1] = x2 * c + x1 * sn;
}

// ------------------------------------------------------------------
__global__ __launch_bounds__(256) void rope_k_kernel(const float* __restrict__ kv,
                                                     float* __restrict__ kpe) {
    const int gid = blockIdx.x * 256 + threadIdx.x;  // < NTOK*32
    const int i = gid & 31;
    const int row = gid >> 5;
    const int s = row & (SEQ - 1);
    const float freq = powf(THETA_F, -(float)(2 * i) / 64.0f);
    const float ang = (float)s * freq;
    const float c = cosf(ang), sn = sinf(ang);
    const float* src = kv + (size_t)row * D_KVA + KV_RANK + 2 * i;
    const float x1 = src[0], x2 = src[1];
    kpe[(size_t)row * QK_ROPE + 2 * i]     = x1 * c - x2 * sn;
    kpe[(size_t)row * QK_ROPE + 2 * i + 1] = x2 * c + x1 * sn;
}

// ------------------------------------------------------------------
// Flash-style MFMA attention.
// Block = 256 threads (4 waves), handles 64 Q rows of one (b,h).
// Wave w owns Q rows [qbase+16w, qbase+16w+16).
// K-tiles of 32 keys staged in LDS (bf16, XOR-swizzled), V transposed.
// ------------------------------------------------------------------
#define QTILE 64
#define KTILE 32

__global__ __launch_bounds__(256) void attn_mfma(const float* __restrict__ q_all,
                                                 const float* __restrict__ kv_dec,
                                                 const float* __restrict__ kpe,
                                                 float* __restrict__ attn_out) {
    __shared__ unsigned short Klds[KTILE * 128];    // [k][d], 256B rows, swz ((k&7)<<4)
    __shared__ unsigned short Vtlds[128 * KTILE];   // [d][k], 64B rows, swz ((d&3)<<4)
    __shared__ unsigned short Plds[4 * 16 * KTILE]; // per wave [16][32], swz ((r&3)<<4)

    const int qbase = blockIdx.x * QTILE;
    const int h = blockIdx.y;
    const int b = blockIdx.z;
    const int tid = threadIdx.x;
    const int w = tid >> 6;
    const int l = tid & 63;
    const int lr = l & 15;   // fragment row / output col
    const int lg = l >> 4;   // 16-lane group 0..3

    // ---- Q fragments in registers (A-layout: row=lr, d = 32*dc + 8*lg + i) ----
    const float* qrow = q_all + (size_t)(b * SEQ + qbase + 16 * w + lr) * (NHEAD * QK_HEAD) + h * QK_HEAD;
    bf16x8 qf[4];
#pragma unroll
    for (int dc = 0; dc < 4; ++dc) {
        union { unsigned short u[8]; bf16x8 v; } t;
#pragma unroll
        for (int i = 0; i < 8; ++i) t.u[i] = f2bf(qrow[dc * 32 + lg * 8 + i]);
        qf[dc] = t.v;
    }

    f32x4 oacc[8];
#pragma unroll
    for (int ft = 0; ft < 8; ++ft) oacc[ft] = (f32x4){0.f, 0.f, 0.f, 0.f};
    float m_r[4] = {-1e30f, -1e30f, -1e30f, -1e30f};
    float l_r[4] = {0.f, 0.f, 0.f, 0.f};

    const float scale = 0.08838834764831845f;  // 128^-0.5
    const int nkt = qbase / KTILE + 2;

    for (int kt = 0; kt < nkt; ++kt) {
        const int k0 = kt * KTILE;
        __syncthreads();  // previous iteration done with K/V/P LDS

        // ---- stage K tile: rows=keys, cols=d (nope from kv_dec, pe from kpe) ----
#pragma unroll
        for (int i = 0; i < 4; ++i) {
            int idx4 = i * 1024 + tid * 4;
            int r = idx4 >> 7, c = idx4 & 127;
            const float* src = (c < 64)
                ? (kv_dec + (size_t)(b * SEQ + k0 + r) * D_KVB + h * 192 + c)
                : (kpe + (size_t)(b * SEQ + k0 + r) * QK_ROPE + (c - 64));
            float4 v = *(const float4*)src;
            int base = r * 256;
            Klds[(base + (((c + 0) * 2) ^ ((r & 7) << 4))) >> 1] = f2bf(v.x);
            Klds[(base + (((c + 1) * 2) ^ ((r & 7) << 4))) >> 1] = f2bf(v.y);
            Klds[(base + (((c + 2) * 2) ^ ((r & 7) << 4))) >> 1] = f2bf(v.z);
            Klds[(base + (((c + 3) * 2) ^ ((r & 7) << 4))) >> 1] = f2bf(v.w);
        }
        // ---- stage V transposed: Vt[d][k] ----
#pragma unroll
        for (int i = 0; i < 4; ++i) {
            int idx4 = i * 1024 + tid * 4;
            int r = idx4 >> 7, d = idx4 & 127;  // r = key idx, d contiguous
            float4 v = *(const float4*)(kv_dec + (size_t)(b * SEQ + k0 + r) * D_KVB + h * 192 + 64 + d);
            Vtlds[((d + 0) * 64 + ((r * 2) ^ (((d + 0) & 3) << 4))) >> 1] = f2bf(v.x);
            Vtlds[((d + 1) * 64 + ((r * 2) ^ (((d + 1) & 3) << 4))) >> 1] = f2bf(v.y);
            Vtlds[((d + 2) * 64 + ((r * 2) ^ (((d + 2) & 3) << 4))) >> 1] = f2bf(v.z);
            Vtlds[((d + 3) * 64 + ((r * 2) ^ (((d + 3) & 3) << 4))) >> 1] = f2bf(v.w);
        }
        __syncthreads();

        // ---- S = Q K^T  (two 16-col tiles) ----
        f32x4 s0 = (f32x4){0.f, 0.f, 0.f, 0.f};
        f32x4 s1 = (f32x4){0.f, 0.f, 0.f, 0.f};
#pragma unroll
        for (int dc = 0; dc < 4; ++dc) {
            int dbyte = (32 * dc + 8 * lg) * 2;
            int r0 = lr, r1 = lr + 16;
            bf16x8 kf0 = *(const bf16x8*)&Klds[(r0 * 256 + (dbyte ^ ((r0 & 7) << 4))) >> 1];
            bf16x8 kf1 = *(const bf16x8*)&Klds[(r1 * 256 + (dbyte ^ ((r1 & 7) << 4))) >> 1];
            s0 = __builtin_amdgcn_mfma_f32_16x16x32_bf16(qf[dc], kf0, s0, 0, 0, 0);
            s1 = __builtin_amdgcn_mfma_f32_16x16x32_bf16(qf[dc], kf1, s1, 0, 0, 0);
        }

        // ---- online softmax (C-layout: col=lr, row=4*lg+j) ----
        float pscale[4];
#pragma unroll
        for (int j = 0; j < 4; ++j) {
            int qg = qbase + 16 * w + 4 * lg + j;
            float v0 = s0[j] * scale, v1 = s1[j] * scale;
            if (k0 + lr > qg) v0 = -1e30f;
            if (k0 + 16 + lr > qg) v1 = -1e30f;
            float t = fmaxf(v0, v1);
            t = fmaxf(t, __shfl_xor(t, 1));
            t = fmaxf(t, __shfl_xor(t, 2));
            t = fmaxf(t, __shfl_xor(t, 4));
            t = fmaxf(t, __shfl_xor(t, 8));
            float newm = fmaxf(m_r[j], t);
            float sf = __expf(m_r[j] - newm);
            m_r[j] = newm;
            float p0 = __expf(v0 - newm);
            float p1 = __expf(v1 - newm);
            s0[j] = p0; s1[j] = p1;
            float rs = p0 + p1;
            rs += __shfl_xor(rs, 1);
            rs += __shfl_xor(rs, 2);
            rs += __shfl_xor(rs, 4);
            rs += __shfl_xor(rs, 8);
            l_r[j] = l_r[j] * sf + rs;
            pscale[j] = sf;
        }
#pragma unroll
        for (int ft = 0; ft < 8; ++ft) {
#pragma unroll
            for (int j = 0; j < 4; ++j) oacc[ft][j] *= pscale[j];
        }

        // ---- P -> LDS (wave-private), re-layout to A-fragments ----
        unsigned short* pw = Plds + w * 16 * KTILE;
#pragma unroll
        for (int j = 0; j < 4; ++j) {
            int r = 4 * lg + j;
            pw[(r * 64 + (((lr) * 2) ^ ((r & 3) << 4))) >> 1] = f2bf(s0[j]);
            pw[(r * 64 + (((16 + lr) * 2) ^ ((r & 3) << 4))) >> 1] = f2bf(s1[j]);
        }
        __syncthreads();
        bf16x8 pa = *(const bf16x8*)&pw[(lr * 64 + ((16 * lg) ^ ((lr & 3) << 4))) >> 1];

        // ---- PV: oacc[ft] += P[16x32] @ V[32x16] ----
#pragma unroll
        for (int ft = 0; ft < 8; ++ft) {
            int d = ft * 16 + lr;
            bf16x8 vb = *(const bf16x8*)&Vtlds[(d * 64 + ((16 * lg) ^ ((d & 3) << 4))) >> 1];
            oacc[ft] = __builtin_amdgcn_mfma_f32_16x16x32_bf16(pa, vb, oacc[ft], 0, 0, 0);
        }
    }

    // ---- epilogue ----
#pragma unroll
    for (int j = 0; j < 4; ++j) {
        int qg = qbase + 16 * w + 4 * lg + j;
        float inv = 1.0f / l_r[j];
        float* orow = attn_out + (size_t)(b * SEQ + qg) * (NHEAD * V_HEAD) + h * V_HEAD;
#pragma unroll
        for (int ft = 0; ft < 8; ++ft) orow[ft * 16 + lr] = oacc[ft][j] * inv;
    }
}

// ------------------------------------------------------------------
extern "C" void kernel_launch(void* const* d_in, const int* in_sizes, int n_in,
                              void* d_out, int out_size, void* d_ws, size_t ws_size,
                              hipStream_t stream) {
    const float* x         = (const float*)d_in[0];
    const float* w_query   = (const float*)d_in[1];
    const float* wkv_a     = (const float*)d_in[2];
    const float* wkv_b     = (const float*)d_in[3];
    const float* kv_norm_w = (const float*)d_in[4];
    const float* out_proj  = (const float*)d_in[5];
    float* out = (float*)d_out;

    float* ws = (float*)d_ws;
    float* q_all    = ws;                               // NTOK * 2048
    float* kv       = q_all + (size_t)NTOK * 2048;      // NTOK * 576
    float* c_norm   = kv + (size_t)NTOK * D_KVA;        // NTOK * 512
    float* kpe      = c_norm + (size_t)NTOK * KV_RANK;  // NTOK * 64
    float* kv_dec   = kpe + (size_t)NTOK * QK_ROPE;     // NTOK * 3072
    float* attn_out = kv_dec + (size_t)NTOK * D_KVB;    // NTOK * 2048

    dim3 blk(16, 16);

    gemm_f32<<<dim3(2048 / 64, NTOK / 64), blk, 0, stream>>>(x, w_query, q_all, NTOK, 2048, D_IN);
    gemm_f32<<<dim3(D_KVA / 64, NTOK / 64), blk, 0, stream>>>(x, wkv_a, kv, NTOK, D_KVA, D_IN);
    rmsnorm_kernel<<<NTOK, 256, 0, stream>>>(kv, kv_norm_w, c_norm);
    gemm_f32<<<dim3(D_KVB / 64, NTOK / 64), blk, 0, stream>>>(c_norm, wkv_b, kv_dec, NTOK, D_KVB, KV_RANK);
    rope_q_kernel<<<(NTOK * NHEAD * 32) / 256, 256, 0, stream>>>(q_all);
    rope_k_kernel<<<(NTOK * 32) / 256, 256, 0, stream>>>(kv, kpe);
    attn_mfma<<<dim3(SEQ / QTILE, NHEAD, BATCH), 256, 0, stream>>>(q_all, kv_dec, kpe, attn_out);
    gemm_f32<<<dim3(D_OUT / 64, NTOK / 64), blk, 0, stream>>>(attn_out, out_proj, out, NTOK, D_OUT, D_IN);
}

// Round 3
// 679.014 us; speedup vs baseline: 10.2925x; 3.6602x over previous
//
#include <hip/hip_runtime.h>
#include <hip/hip_bf16.h>
#include <math.h>

#define BATCH   2
#define SEQ     2048
#define D_IN    2048
#define NHEAD   16
#define QK_ROPE 64
#define QK_NOPE 64
#define QK_HEAD 128
#define V_HEAD  128
#define KV_RANK 512
#define D_KVA_P 640          // padded 576 -> 640
#define D_KVB   3072
#define NTOK    (BATCH*SEQ)  // 4096
#define EPS_F   1e-6f

typedef unsigned short u16;
typedef short bf16x8 __attribute__((ext_vector_type(8)));
typedef float f32x4  __attribute__((ext_vector_type(4)));

__device__ __forceinline__ u16 f2bf(float f) {
    unsigned u = __float_as_uint(f);
    return (u16)((u + 0x7fffu + ((u >> 16) & 1u)) >> 16);
}
__device__ __forceinline__ float bf2f(u16 u) {
    return __uint_as_float(((unsigned)u) << 16);
}
__device__ __forceinline__ void gload16(const void* g, void* l) {
    __builtin_amdgcn_global_load_lds((const __attribute__((address_space(1))) unsigned int*)g,
                                     (__attribute__((address_space(3))) unsigned int*)l, 16, 0, 0);
}

// ---------------- fp32 -> bf16 flat convert (4 elems/thread) ----------------
__global__ __launch_bounds__(256) void convert_bf16(const float* __restrict__ src,
                                                    u16* __restrict__ dst, int n4) {
    int gid = blockIdx.x * 256 + threadIdx.x;
    if (gid >= n4) return;
    float4 v = ((const float4*)src)[gid];
    unsigned lo = (unsigned)f2bf(v.x) | ((unsigned)f2bf(v.y) << 16);
    unsigned hi = (unsigned)f2bf(v.z) | ((unsigned)f2bf(v.w) << 16);
    ((uint2*)dst)[gid] = make_uint2(lo, hi);
}

// -------- transpose+convert: src fp32 [K][N] -> dst bf16 [Npad][K] ----------
// grid.x covers Npad/32 (pad rows n>=N written as zero), grid.y = K/32.
__global__ __launch_bounds__(256) void transpose_bf16(const float* __restrict__ src,
                                                      u16* __restrict__ dst,
                                                      int N, int K) {
    __shared__ float tile[32][33];
    const int nb = blockIdx.x * 32, kb = blockIdx.y * 32;
    const int tx = threadIdx.x, ty = threadIdx.y;  // 32 x 8
#pragma unroll
    for (int i = 0; i < 4; ++i) {
        int k = kb + ty + 8 * i, n = nb + tx;
        tile[ty + 8 * i][tx] = (n < N) ? src[(size_t)k * N + n] : 0.f;
    }
    __syncthreads();
#pragma unroll
    for (int i = 0; i < 4; ++i) {
        int n = nb + ty + 8 * i, k = kb + tx;
        dst[(size_t)n * K + k] = f2bf(tile[tx][ty + 8 * i]);
    }
}

// ---------------- RoPE cos/sin table: tab[(s*32+i)*2] = cos, +1 = sin -------
__global__ __launch_bounds__(256) void rope_table_kernel(float* __restrict__ tab) {
    int gid = blockIdx.x * 256 + threadIdx.x;  // < SEQ*32
    int i = gid & 31, s = gid >> 5;
    float freq = __expf(-(float)(2 * i) / 64.0f * 9.210340371976184f);
    float ang = (float)s * freq;
    tab[2 * gid]     = cosf(ang);
    tab[2 * gid + 1] = sinf(ang);
}

// ---------------- m97-style bf16 GEMM: C = A[M,K] @ BT[N,K]^T ----------------
// 128x128 tile, 4 waves (2x2), BK=32, linear LDS + global_load_lds(16).
template <bool OBF>
__global__ __launch_bounds__(256) void gemm_bf16(const u16* __restrict__ A,
                                                 const u16* __restrict__ BT,
                                                 float* __restrict__ C,
                                                 u16* __restrict__ Cbf,
                                                 int M, int N, int K) {
    __shared__ u16 As[128 * 32];
    __shared__ u16 Bs[128 * 32];
    const int tid = threadIdx.x;
    const int w = tid >> 6, l = tid & 63;
    const int lr = l & 15, lg = l >> 4;
    const int wr = w >> 1, wc = w & 1;
    const int row0 = blockIdx.y * 128, col0 = blockIdx.x * 128;

    f32x4 acc[4][4];
#pragma unroll
    for (int a = 0; a < 4; ++a)
#pragma unroll
        for (int b = 0; b < 4; ++b) acc[a][b] = (f32x4){0.f, 0.f, 0.f, 0.f};

    const u16* ga = A + (size_t)(row0 + 32 * w + (l >> 2)) * K + 8 * (l & 3);
    const u16* gb = BT + (size_t)(col0 + 32 * w + (l >> 2)) * K + 8 * (l & 3);
    u16* la = As + w * 1024;
    u16* lb = Bs + w * 1024;

    for (int k0 = 0; k0 < K; k0 += 32) {
        __syncthreads();
        gload16(ga + k0, la);
        gload16(ga + (size_t)16 * K + k0, la + 512);
        gload16(gb + k0, lb);
        gload16(gb + (size_t)16 * K + k0, lb + 512);
        __syncthreads();
        bf16x8 af[4], bfr[4];
#pragma unroll
        for (int mi = 0; mi < 4; ++mi)
            af[mi] = *(const bf16x8*)&As[(64 * wr + 16 * mi + lr) * 32 + 8 * lg];
#pragma unroll
        for (int ni = 0; ni < 4; ++ni)
            bfr[ni] = *(const bf16x8*)&Bs[(64 * wc + 16 * ni + lr) * 32 + 8 * lg];
#pragma unroll
        for (int mi = 0; mi < 4; ++mi)
#pragma unroll
            for (int ni = 0; ni < 4; ++ni)
                acc[mi][ni] = __builtin_amdgcn_mfma_f32_16x16x32_bf16(af[mi], bfr[ni], acc[mi][ni], 0, 0, 0);
    }
#pragma unroll
    for (int mi = 0; mi < 4; ++mi)
#pragma unroll
        for (int ni = 0; ni < 4; ++ni)
#pragma unroll
            for (int j = 0; j < 4; ++j) {
                int r = row0 + 64 * wr + 16 * mi + 4 * lg + j;
                int c = col0 + 64 * wc + 16 * ni + lr;
                if (OBF) Cbf[(size_t)r * N + c] = f2bf(acc[mi][ni][j]);
                else     C[(size_t)r * N + c] = acc[mi][ni][j];
            }
}

// ---------------- RMS norm: kv fp32 [NTOK][640] cols 0..511 -> bf16 ---------
__global__ __launch_bounds__(256) void rmsnorm_bf(const float* __restrict__ kv,
                                                  const float* __restrict__ w,
                                                  u16* __restrict__ c_norm) {
    __shared__ float red[256];
    const int row = blockIdx.x, t = threadIdx.x;
    const float* src = kv + (size_t)row * D_KVA_P;
    float v0 = src[t], v1 = src[t + 256];
    red[t] = v0 * v0 + v1 * v1;
    __syncthreads();
    for (int s = 128; s > 0; s >>= 1) {
        if (t < s) red[t] += red[t + s];
        __syncthreads();
    }
    const float inv = rsqrtf(red[0] / (float)KV_RANK + EPS_F);
    u16* dst = c_norm + (size_t)row * KV_RANK;
    dst[t]       = f2bf(v0 * inv * w[t]);
    dst[t + 256] = f2bf(v1 * inv * w[t + 256]);
}

// ---------------- RoPE on q_bf in place (pe half of each head) --------------
__global__ __launch_bounds__(256) void rope_q_kernel(u16* __restrict__ q_bf,
                                                     const float* __restrict__ tab) {
    const int gid = blockIdx.x * 256 + threadIdx.x;  // < NTOK*16*32
    const int i = gid & 31;
    const int h = (gid >> 5) & (NHEAD - 1);
    const int row = gid >> 9;
    const int s = row & (SEQ - 1);
    const float c = tab[(s * 32 + i) * 2], sn = tab[(s * 32 + i) * 2 + 1];
    u16* p = q_bf + (size_t)row * 2048 + h * QK_HEAD + QK_NOPE + 2 * i;
    float x1 = bf2f(p[0]), x2 = bf2f(p[1]);
    p[0] = f2bf(x1 * c - x2 * sn);
    p[1] = f2bf(x2 * c + x1 * sn);
}

// ---------------- build K_all bf16 [bh][s][128] = (k_nope | roped k_pe) -----
__global__ __launch_bounds__(256) void build_k_kernel(const u16* __restrict__ kvdec_bf,
                                                      const float* __restrict__ kv,
                                                      const float* __restrict__ tab,
                                                      u16* __restrict__ K_all) {
    const int gid = blockIdx.x * 256 + threadIdx.x;  // < 32*2048*32 = 2^21
    const int dq = gid & 31;
    const int s = (gid >> 5) & (SEQ - 1);
    const int bh = gid >> 16;
    const int b = bh >> 4, h = bh & 15;
    const size_t bs_row = (size_t)b * SEQ + s;
    u16* dst = K_all + ((size_t)bh * SEQ + s) * 128 + 4 * dq;
    if (dq < 16) {
        // k_nope: direct bf16 copy from kv_dec
        const u16* src = kvdec_bf + bs_row * D_KVB + h * 192 + 4 * dq;
        *(ushort2*)dst = *(const ushort2*)src;
        *(ushort2*)(dst + 2) = *(const ushort2*)(src + 2);
    } else {
        const int j0 = 4 * dq - 64;          // 0,4,..,60
        const int i0 = j0 >> 1;              // even
        float4 v = *(const float4*)(kv + bs_row * D_KVA_P + KV_RANK + j0);
        float c0 = tab[(s * 32 + i0) * 2],     s0 = tab[(s * 32 + i0) * 2 + 1];
        float c1 = tab[(s * 32 + i0 + 1) * 2], s1 = tab[(s * 32 + i0 + 1) * 2 + 1];
        dst[0] = f2bf(v.x * c0 - v.y * s0);
        dst[1] = f2bf(v.y * c0 + v.x * s0);
        dst[2] = f2bf(v.z * c1 - v.w * s1);
        dst[3] = f2bf(v.w * c1 + v.z * s1);
    }
}

// ---------------- build Vt bf16 [bh][d=128][s] from kv_dec ------------------
__global__ __launch_bounds__(256) void build_vt_kernel(const u16* __restrict__ kvdec_bf,
                                                       u16* __restrict__ Vt) {
    __shared__ u16 tile[64][136];
    const int sb = blockIdx.x * 64;
    const int bh = blockIdx.y;
    const int b = bh >> 4, h = bh & 15;
    const int tid = threadIdx.x;
#pragma unroll
    for (int i = 0; i < 4; ++i) {
        int s_loc = (tid >> 4) + 16 * i;
        int d8 = (tid & 15) * 8;
        bf16x8 v = *(const bf16x8*)(kvdec_bf + ((size_t)b * SEQ + sb + s_loc) * D_KVB + h * 192 + 64 + d8);
        *(bf16x8*)&tile[s_loc][d8] = v;
    }
    __syncthreads();
    const int d = tid >> 1;
    const int so = (tid & 1) * 32;
    union { u16 u[32]; bf16x8 v[4]; } out;
#pragma unroll
    for (int j = 0; j < 32; ++j) out.u[j] = tile[so + j][d];
    u16* dst = Vt + ((size_t)bh * 128 + d) * SEQ + sb + so;
#pragma unroll
    for (int k = 0; k < 4; ++k) *(bf16x8*)(dst + 8 * k) = out.v[k];
}

// ---------------- flash attention, fragments direct from global -------------
#define QTILE 64
#define KTILE 32

__global__ __launch_bounds__(256) void attn_mfma(const u16* __restrict__ q_bf,
                                                 const u16* __restrict__ K_all,
                                                 const u16* __restrict__ Vt,
                                                 u16* __restrict__ attn_bf) {
    __shared__ u16 Plds[4 * 16 * KTILE];
    const int qbase = blockIdx.x * QTILE;
    const int h = blockIdx.y, b = blockIdx.z;
    const int tid = threadIdx.x;
    const int w = tid >> 6, l = tid & 63;
    const int lr = l & 15, lg = l >> 4;
    const int bh = b * NHEAD + h;
    const u16* Kb = K_all + (size_t)bh * SEQ * 128;
    const u16* Vb = Vt + (size_t)bh * 128 * SEQ;

    const u16* qrow = q_bf + (size_t)(b * SEQ + qbase + 16 * w + lr) * 2048 + h * QK_HEAD;
    bf16x8 qf[4];
#pragma unroll
    for (int dc = 0; dc < 4; ++dc) qf[dc] = *(const bf16x8*)(qrow + dc * 32 + lg * 8);

    f32x4 oacc[8];
#pragma unroll
    for (int ft = 0; ft < 8; ++ft) oacc[ft] = (f32x4){0.f, 0.f, 0.f, 0.f};
    float m_r[4] = {-1e30f, -1e30f, -1e30f, -1e30f};
    float l_r[4] = {0.f, 0.f, 0.f, 0.f};
    const float scale = 0.08838834764831845f;
    const int nkt = qbase / KTILE + 2;

    u16* pw = Plds + w * 16 * KTILE;

    for (int kt = 0; kt < nkt; ++kt) {
        const int k0 = kt * KTILE;
        f32x4 s0 = (f32x4){0.f, 0.f, 0.f, 0.f};
        f32x4 s1 = (f32x4){0.f, 0.f, 0.f, 0.f};
#pragma unroll
        for (int dc = 0; dc < 4; ++dc) {
            bf16x8 kf0 = *(const bf16x8*)(Kb + (size_t)(k0 + lr) * 128 + dc * 32 + lg * 8);
            bf16x8 kf1 = *(const bf16x8*)(Kb + (size_t)(k0 + 16 + lr) * 128 + dc * 32 + lg * 8);
            s0 = __builtin_amdgcn_mfma_f32_16x16x32_bf16(qf[dc], kf0, s0, 0, 0, 0);
            s1 = __builtin_amdgcn_mfma_f32_16x16x32_bf16(qf[dc], kf1, s1, 0, 0, 0);
        }
        float pscale[4];
#pragma unroll
        for (int j = 0; j < 4; ++j) {
            int qg = qbase + 16 * w + 4 * lg + j;
            float v0 = s0[j] * scale, v1 = s1[j] * scale;
            if (k0 + lr > qg) v0 = -1e30f;
            if (k0 + 16 + lr > qg) v1 = -1e30f;
            float t = fmaxf(v0, v1);
            t = fmaxf(t, __shfl_xor(t, 1));
            t = fmaxf(t, __shfl_xor(t, 2));
            t = fmaxf(t, __shfl_xor(t, 4));
            t = fmaxf(t, __shfl_xor(t, 8));
            float newm = fmaxf(m_r[j], t);
            float sf = __expf(m_r[j] - newm);
            m_r[j] = newm;
            float p0 = __expf(v0 - newm);
            float p1 = __expf(v1 - newm);
            s0[j] = p0; s1[j] = p1;
            float rs = p0 + p1;
            rs += __shfl_xor(rs, 1);
            rs += __shfl_xor(rs, 2);
            rs += __shfl_xor(rs, 4);
            rs += __shfl_xor(rs, 8);
            l_r[j] = l_r[j] * sf + rs;
            pscale[j] = sf;
        }
#pragma unroll
        for (int ft = 0; ft < 8; ++ft)
#pragma unroll
            for (int j = 0; j < 4; ++j) oacc[ft][j] *= pscale[j];

        // P -> wave-private LDS, re-layout to A-fragment
#pragma unroll
        for (int j = 0; j < 4; ++j) {
            int r = 4 * lg + j;
            pw[(r * 64 + ((lr * 2) ^ ((r & 3) << 4))) >> 1] = f2bf(s0[j]);
            pw[(r * 64 + (((16 + lr) * 2) ^ ((r & 3) << 4))) >> 1] = f2bf(s1[j]);
        }
        asm volatile("s_waitcnt lgkmcnt(0)" ::: "memory");
        bf16x8 pa = *(const bf16x8*)&pw[(lr * 64 + ((16 * lg) ^ ((lr & 3) << 4))) >> 1];

#pragma unroll
        for (int ft = 0; ft < 8; ++ft) {
            int d = ft * 16 + lr;
            bf16x8 vb = *(const bf16x8*)(Vb + (size_t)d * SEQ + k0 + 8 * lg);
            oacc[ft] = __builtin_amdgcn_mfma_f32_16x16x32_bf16(pa, vb, oacc[ft], 0, 0, 0);
        }
    }

#pragma unroll
    for (int j = 0; j < 4; ++j) {
        int qg = qbase + 16 * w + 4 * lg + j;
        float inv = 1.0f / l_r[j];
        u16* orow = attn_bf + (size_t)(b * SEQ + qg) * 2048 + h * V_HEAD;
#pragma unroll
        for (int ft = 0; ft < 8; ++ft) orow[ft * 16 + lr] = f2bf(oacc[ft][j] * inv);
    }
}

// ------------------------------------------------------------------
extern "C" void kernel_launch(void* const* d_in, const int* in_sizes, int n_in,
                              void* d_out, int out_size, void* d_ws, size_t ws_size,
                              hipStream_t stream) {
    const float* x         = (const float*)d_in[0];
    const float* w_query   = (const float*)d_in[1];
    const float* wkv_a     = (const float*)d_in[2];
    const float* wkv_b     = (const float*)d_in[3];
    const float* kv_norm_w = (const float*)d_in[4];
    const float* out_proj  = (const float*)d_in[5];

    u16* x_bf     = (u16*)d_ws;                       // 8M u16 (aliased by attn_bf)
    u16* q_bf     = x_bf + (size_t)8388608;           // 8M
    u16* c_norm   = q_bf + (size_t)8388608;           // 2M
    u16* kvdec_bf = c_norm + (size_t)2097152;         // 12.58M
    u16* K_all    = kvdec_bf + (size_t)12582912;      // 8.39M
    u16* Vt       = K_all + (size_t)8388608;          // 8.39M
    u16* wqT      = Vt + (size_t)8388608;             // 4M
    u16* wkvaT    = wqT + (size_t)4194304;            // 1.31M
    u16* wkvbT    = wkvaT + (size_t)1310720;          // 1.57M
    u16* opT      = wkvbT + (size_t)1572864;          // 4M
    float* kv     = (float*)(opT + (size_t)4194304);  // 2.62M floats
    float* tab    = kv + (size_t)2621440;             // 131072 floats
    u16* attn_bf  = x_bf;                             // alias (x_bf dead after kv GEMM)
    float* out = (float*)d_out;

    dim3 tb(32, 8);

    convert_bf16<<<8192, 256, 0, stream>>>(x, x_bf, 2097152);
    transpose_bf16<<<dim3(64, 64), tb, 0, stream>>>(w_query, wqT, 2048, 2048);
    transpose_bf16<<<dim3(20, 64), tb, 0, stream>>>(wkv_a, wkvaT, 576, 2048);   // pad to 640 rows
    transpose_bf16<<<dim3(96, 16), tb, 0, stream>>>(wkv_b, wkvbT, 3072, 512);
    transpose_bf16<<<dim3(64, 64), tb, 0, stream>>>(out_proj, opT, 2048, 2048);
    rope_table_kernel<<<256, 256, 0, stream>>>(tab);

    gemm_bf16<true><<<dim3(16, 32), 256, 0, stream>>>(x_bf, wqT, nullptr, q_bf, NTOK, 2048, 2048);
    gemm_bf16<false><<<dim3(5, 32), 256, 0, stream>>>(x_bf, wkvaT, kv, nullptr, NTOK, D_KVA_P, 2048);
    rmsnorm_bf<<<NTOK, 256, 0, stream>>>(kv, kv_norm_w, c_norm);
    gemm_bf16<true><<<dim3(24, 32), 256, 0, stream>>>(c_norm, wkvbT, nullptr, kvdec_bf, NTOK, D_KVB, KV_RANK);

    rope_q_kernel<<<8192, 256, 0, stream>>>(q_bf, tab);
    build_k_kernel<<<8192, 256, 0, stream>>>(kvdec_bf, kv, tab, K_all);
    build_vt_kernel<<<dim3(32, 32), 256, 0, stream>>>(kvdec_bf, Vt);

    attn_mfma<<<dim3(SEQ / QTILE, NHEAD, BATCH), 256, 0, stream>>>(q_bf, K_all, Vt, attn_bf);

    gemm_bf16<false><<<dim3(16, 32), 256, 0, stream>>>(attn_bf, opT, out, nullptr, NTOK, 2048, 2048);
}